// Round 11
// baseline (488.410 us; speedup 1.0000x reference)
//
#include <hip/hip_runtime.h>
#include <hip/hip_bf16.h>

// ---------------------------------------------------------------------------
// DecoderRNN: emb gather -> x_proj GEMM (split-bf16 MFMA, padded-LDS reg
// staging) -> ONE fused kernel: blocks 0-63 = persistent dataflow LSTM
// (per-producer flags x8 replicas; R11: Af stores -> ISSUE-BARRIER -> rec
// flags with no drain; consumers poison-validate + sc1-retry (rare)),
// blocks 64-255 = persistent logits-GEMM workers on t-major hs.
// B=64 T=32 E=512 H=512 V=16000
// ---------------------------------------------------------------------------

typedef __attribute__((ext_vector_type(8))) short short8v;
typedef __attribute__((ext_vector_type(4))) short short4v;
typedef __attribute__((ext_vector_type(4))) float float4v;
typedef __attribute__((ext_vector_type(4))) int   int4v;

static __device__ __forceinline__ short f2bf(float v) {
    __hip_bfloat16 b = __float2bfloat16(v);
    return *reinterpret_cast<short*>(&b);
}
static __device__ __forceinline__ float bf2f(short s) {
    __hip_bfloat16 b = *reinterpret_cast<__hip_bfloat16*>(&s);
    return __bfloat162float(b);
}

// ---------------------------------------------------------------------------
// Prep kernels
// ---------------------------------------------------------------------------

__global__ __launch_bounds__(256) void prep_x_kernel(
    const float* __restrict__ features, const int* __restrict__ captions,
    const float* __restrict__ emb, short* __restrict__ A1)
{
    int m = blockIdx.x;            // 0..2047
    int b = m >> 5, t = m & 31;
    const float* src = (t == 0) ? (features + (long)b * 512)
                                : (emb + (long)captions[b * 32 + t] * 512);
    long base = (long)m * 1536;
    for (int k = threadIdx.x; k < 512; k += 256) {
        float v = src[k];
        short hi = f2bf(v);
        short lo = f2bf(v - bf2f(hi));
        A1[base + k]        = hi;
        A1[base + 512 + k]  = lo;
        A1[base + 1024 + k] = hi;
    }
}

__global__ __launch_bounds__(256) void prep_w_kernel(
    const float* __restrict__ W_ih, short* __restrict__ B1)
{
    int n = blockIdx.x;            // 0..2047
    long base = (long)n * 1536;
    const float* src = W_ih + (long)n * 512;
    for (int k = threadIdx.x; k < 512; k += 256) {
        float v = src[k];
        short hi = f2bf(v);
        short lo = f2bf(v - bf2f(hi));
        B1[base + k]        = hi;
        B1[base + 512 + k]  = hi;
        B1[base + 1024 + k] = lo;
    }
}

__global__ __launch_bounds__(256) void prep_bias_kernel(
    const float* __restrict__ b_ih, const float* __restrict__ b_hh,
    float* __restrict__ biasc, int* __restrict__ flags)
{
    int g = blockIdx.x * 256 + threadIdx.x;
    if (g < 2048) biasc[g] = b_ih[g] + b_hh[g];
    if (g < 1024) flags[g] = 0;   // [0..511] rec replicas, [512..1023] wrk
}

__global__ __launch_bounds__(256) void prep_wlin_kernel(
    const float* __restrict__ W_lin, short* __restrict__ Wl)
{
    int v = blockIdx.x;            // 0..15999
    long base = (long)v * 512;
    for (int k = threadIdx.x; k < 512; k += 256) {
        Wl[base + k] = f2bf(W_lin[base + k]);
    }
}

// ---------------------------------------------------------------------------
// Fragment layout for the LSTM recurrence ([hi | lo] compressed, 32 k-tiles).
// Af buffer (per step): [4 mt][32 kt][64 lane][8] bf16 = 128 KB
// W2 (per block): [2 nt][32 kt][64 lane][8] bf16 = 64 KB.
// ---------------------------------------------------------------------------
#define AF2_FRAGS 8192           // 4 * 32 * 64
#define W3_FRAGS_PER_BLK 4096    // 2 * 32 * 64

static __device__ __forceinline__ int frag2_idx(int tile, int k, int row15, int isLo)
{
    return ((tile * 32 + (k >> 5) + isLo * 16) * 64
            + ((k >> 2) & 3) * 16 + row15) * 8
           + (k & 3) + ((k >> 4) & 1) * 4;
}

__global__ __launch_bounds__(256) void prep_whh_kernel(
    const float* __restrict__ W_hh, short* __restrict__ W2)
{
    int n  = blockIdx.x;                 // 0..2047 gate-row
    int s  = n >> 9, jg = n & 511;
    int ob = jg >> 3, u = jg & 7;
    int nl = s * 8 + u;
    int nt = nl >> 4, rr = nl & 15;
    short* dst = W2 + (long)ob * (W3_FRAGS_PER_BLK * 8);
    for (int k0 = threadIdx.x; k0 < 512; k0 += 256) {
        float v  = W_hh[(long)n * 512 + k0];
        short hi = f2bf(v);
        short lo = f2bf(v - bf2f(hi));
        dst[frag2_idx(nt, k0, rr, 0)] = hi;
        dst[frag2_idx(nt, k0, rr, 1)] = lo;
    }
}

// Poison the 31 per-step h-fragment buffers with 0xFFFFFFFF.  h = o*tanh(c)
// and its bf16 lo-residual are finite, so no bf16 half can be 0xFFFF ->
// "dword == -1" uniquely means "not yet written this launch".  sc0 sc1
// write-through so the poison is authoritative at the MALL.
__global__ __launch_bounds__(256) void poison_af_kernel(short* __restrict__ Af)
{
    int idx = blockIdx.x * 256 + threadIdx.x;         // one 16B chunk each
    const int total = 31 * AF2_FRAGS * 8 * 2 / 16;    // 253952
    if (idx < total) {
        int4v pv = {-1, -1, -1, -1};
        char* p = (char*)Af + (size_t)idx * 16;
        asm volatile("global_store_dwordx4 %0, %1, off sc0 sc1"
                     :: "v"(p), "v"(pv) : "memory");
    }
}

// ---------------------------------------------------------------------------
// bf16 MFMA GEMM (x_proj only):  C[m][n] = sum_k A[m][k]*B[n][k] + bias[n]
// 128x128 tile, 4 waves, BK=64, padded LDS (GLDT=72), reg staging.
// ---------------------------------------------------------------------------
#define GBK 64
#define GPAD 8
#define GLDT (GBK + GPAD)   // 72 shorts per row

__global__ __launch_bounds__(256) void gemm_bf16_kernel(
    const short* __restrict__ A, const short* __restrict__ B,
    const float* __restrict__ bias, float* __restrict__ C,
    int M, int N, int K)
{
    __shared__ short As[128 * GLDT];
    __shared__ short Bs[128 * GLDT];

    const int tid  = threadIdx.x;
    const int bm   = blockIdx.x, bn = blockIdx.y;
    const int lane = tid & 63, wave = tid >> 6;
    const int wm   = wave >> 1, wn = wave & 1;
    const int r    = lane & 15, q = lane >> 4;

    float4v acc[4][4];
#pragma unroll
    for (int i = 0; i < 4; ++i)
#pragma unroll
        for (int j = 0; j < 4; ++j) acc[i][j] = (float4v)(0.0f);

    const long arow0 = (long)bm * 128;
    const long brow0 = (long)bn * 128;

    for (int kt = 0; kt < K; kt += GBK) {
        __syncthreads();
#pragma unroll
        for (int it = 0; it < 4; ++it) {
            int task = tid + it * 256;       // 0..1023
            int row = task >> 3, seg = task & 7;
            const short* gA = A + (arow0 + row) * (long)K + kt + seg * 8;
            *(short8v*)&As[row * GLDT + seg * 8] = *(const short8v*)gA;
            const short* gB = B + (brow0 + row) * (long)K + kt + seg * 8;
            *(short8v*)&Bs[row * GLDT + seg * 8] = *(const short8v*)gB;
        }
        __syncthreads();
#pragma unroll
        for (int kc = 0; kc < GBK; kc += 32) {
            short8v af[4], bf[4];
#pragma unroll
            for (int i = 0; i < 4; ++i) {
                int arow = wm * 64 + i * 16 + r;
                union { short4v h[2]; short8v v; } ua;
                ua.h[0] = *(short4v*)&As[arow * GLDT + kc + q * 4];
                ua.h[1] = *(short4v*)&As[arow * GLDT + kc + 16 + q * 4];
                af[i] = ua.v;
                int brow = wn * 64 + i * 16 + r;
                union { short4v h[2]; short8v v; } ub;
                ub.h[0] = *(short4v*)&Bs[brow * GLDT + kc + q * 4];
                ub.h[1] = *(short4v*)&Bs[brow * GLDT + kc + 16 + q * 4];
                bf[i] = ub.v;
            }
#pragma unroll
            for (int i = 0; i < 4; ++i)
#pragma unroll
                for (int j = 0; j < 4; ++j)
                    acc[i][j] = __builtin_amdgcn_mfma_f32_16x16x32_bf16(
                        af[i], bf[j], acc[i][j], 0, 0, 0);
        }
    }

#pragma unroll
    for (int j = 0; j < 4; ++j) {
        int col = bn * 128 + wn * 64 + j * 16 + r;
        float bv = bias[col];
#pragma unroll
        for (int i = 0; i < 4; ++i) {
            int row0 = bm * 128 + wm * 64 + i * 16 + q * 4;
#pragma unroll
            for (int reg = 0; reg < 4; ++reg) {
                C[(long)(row0 + reg) * N + col] = acc[i][j][reg] + bv;
            }
        }
    }
}

// ---------------------------------------------------------------------------
// Fused persistent kernel, 256 blocks x 512 threads (1 block/CU):
//  blocks 0-63:  dataflow LSTM.  R11 publication:
//    Af sc1 stores -> raw s_barrier (all stores ISSUED) -> rec flags (no
//    drain; consumers poison-validate, sc1-retry on rare races) -> hs2 sc1
//    stores -> vmcnt(0) drain -> raw s_barrier -> wrk flags (full release).
//  blocks 64-255: persistent logits-GEMM workers, poll wrk flags (replica
//    bid&7) with s_sleep(16).
// ---------------------------------------------------------------------------
__global__ __launch_bounds__(512, 1) void fused_lstm_logits_kernel(
    const float* __restrict__ x_proj, const short* __restrict__ W2,
    short* __restrict__ Af, short* __restrict__ hs2,
    int* __restrict__ flags, const short* __restrict__ Wl,
    const float* __restrict__ b_lin, float* __restrict__ out)
{
    // LSTM-side LDS
    __shared__ __align__(16) short Wf[W3_FRAGS_PER_BLK * 8];  // 64 KB
    __shared__ float gl[32 * 65];                             // 8.3 KB
    __shared__ short Hs[64][12];                              // 1.5 KB
    __shared__ short Ls[64][12];                              // 1.5 KB
    // worker-side LDS
    __shared__ short As[128 * GLDT];                          // 18 KB
    __shared__ short Bs[128 * GLDT];                          // 18 KB

    const int tid  = threadIdx.x;
    const int bid  = blockIdx.x;
    const int lane = tid & 63;
    const int wave = tid >> 6;        // 0..7
    const int r    = lane & 15, q = lane >> 4;
    const int frep = (bid & 7) * 64;  // flag replica base

    if (bid < 64) {
        // ===================== LSTM path =====================
        const int mt   = wave & 3;        // batch tile (16 rows each)
        const int nt   = wave >> 2;       // gate-col tile (16 cols each)
        const int j0   = bid * 8;
        const int aq   = bid & 3;         // k5 block within 32-wide k-tile
        const int kt0  = bid >> 2;        // k-tile our jj values live in

        {
            const short8v* src = (const short8v*)W2 + (size_t)bid * W3_FRAGS_PER_BLK;
            short8v* dst = (short8v*)Wf;
            for (int i = tid; i < W3_FRAGS_PER_BLK; i += 512) dst[i] = src[i];
        }
        __syncthreads();

        const int bb  = lane;
        const int ub  = wave;             // 0..7
        const int jj  = j0 + ub;
        float c_reg = 0.0f;

        // repack-task decode (threads 0..255): one 8B Af store each
        const int rdt  = (tid >> 7) & 1;          // 0=hi, 1=lo
        const int rmt  = (tid >> 5) & 3;
        const int rrb  = (tid >> 1) & 15;
        const int rhf  = tid & 1;
        const int rbb  = rmt * 16 + rrb;
        const int rq5  = (2 * aq + rhf) & 3;
        const size_t rfrag =
            (size_t)((rmt * 32 + kt0 + rdt * 16) * 64 + rq5 * 16 + rrb);
        const size_t roff = rfrag * 8 + (size_t)(aq >> 1) * 4;

        const short8v* Bw = (const short8v*)Wf + nt * 32 * 64 + lane;

        float xc0, xc1, xc2, xc3;
        {
            const float* xp = x_proj + ((size_t)bb * 32 + 0) * 2048 + jj;
            xc0 = xp[0]; xc1 = xp[512]; xc2 = xp[1024]; xc3 = xp[1536];
        }

        for (int t = 0; t < 32; ++t) {
            float xn0 = 0.f, xn1 = 0.f, xn2 = 0.f, xn3 = 0.f;
            if (t < 31) {
                const float* xp = x_proj + ((size_t)bb * 32 + (t + 1)) * 2048 + jj;
                xn0 = xp[0]; xn1 = xp[512]; xn2 = xp[1024]; xn3 = xp[1536];
            }

            float4v acc = (float4v)(0.0f);
            if (t > 0) {
                const short8v* Ab = (const short8v*)Af
                    + (size_t)(t - 1) * AF2_FRAGS + mt * 32 * 64 + lane;
                union frag_u { int4v i; short8v s; };
                frag_u fha[16], fla[16];

                unsigned long long ready;
                {
                    int myf = __hip_atomic_load(&flags[frep + lane], __ATOMIC_RELAXED,
                                                __HIP_MEMORY_SCOPE_AGENT);
                    ready = __ballot(myf >= t);
                }
#pragma unroll
                for (int g = 0; g < 4; ++g) {
                    const unsigned long long need = 0xFFFFull << (g * 16);
                    while ((ready & need) != need) {
                        int myf = __hip_atomic_load(&flags[frep + lane], __ATOMIC_RELAXED,
                                                    __HIP_MEMORY_SCOPE_AGENT);
                        ready = __ballot(myf >= t);
                    }
                    asm volatile("" ::: "memory");
#pragma unroll
                    for (int k = 0; k < 4; ++k) {
                        fha[g * 4 + k].s = Ab[(g * 4 + k) * 64];
                        fla[g * 4 + k].s = Ab[(16 + g * 4 + k) * 64];
                    }
                }

                // poison validation: rec flags fire after ISSUE (not drain),
                // so data can trail by fabric skew only -> races are rare.
                // dwords x/z cover the two 8B store halves of each fragment.
                // Retry via L2-BYPASS loads (plain loads may have cached a
                // poison line).
                {
                    const char* abase = (const char*)Ab;
                    while (true) {
                        int ok = 1;
#pragma unroll
                        for (int k = 0; k < 16; ++k) {
                            ok &= (fha[k].i.x != -1) & (fha[k].i.z != -1)
                                & (fla[k].i.x != -1) & (fla[k].i.z != -1);
                        }
                        if (__all(ok)) break;
#pragma unroll
                        for (int k = 0; k < 16; ++k) {
                            asm volatile("global_load_dwordx4 %0, %1, off sc0 sc1"
                                         : "=v"(fha[k].i)
                                         : "v"(abase + (size_t)k * 1024)
                                         : "memory");
                            asm volatile("global_load_dwordx4 %0, %1, off sc0 sc1"
                                         : "=v"(fla[k].i)
                                         : "v"(abase + 16384 + (size_t)k * 1024)
                                         : "memory");
                        }
                        asm volatile("s_waitcnt vmcnt(0)" ::: "memory");
                        __builtin_amdgcn_sched_barrier(0);
                    }
                }

                float4v a0 = (float4v)(0.0f), a1 = (float4v)(0.0f), a2 = (float4v)(0.0f);
#pragma unroll
                for (int kt = 0; kt < 16; ++kt) {
                    short8v Bhi = Bw[kt * 64];
                    short8v Blo = Bw[(16 + kt) * 64];
                    a0 = __builtin_amdgcn_mfma_f32_16x16x32_bf16(fha[kt].s, Bhi, a0, 0, 0, 0);
                    a1 = __builtin_amdgcn_mfma_f32_16x16x32_bf16(fla[kt].s, Bhi, a1, 0, 0, 0);
                    a2 = __builtin_amdgcn_mfma_f32_16x16x32_bf16(fha[kt].s, Blo, a2, 0, 0, 0);
                }
                acc = a0 + a1 + a2;
            }

            __syncthreads();
#pragma unroll
            for (int reg = 0; reg < 4; ++reg)
                gl[(nt * 16 + r) * 65 + mt * 16 + q * 4 + reg] = acc[reg];
            __syncthreads();

            float iv = gl[(0  + ub) * 65 + bb] + xc0;
            float fv = gl[(8  + ub) * 65 + bb] + xc1;
            float gv = gl[(16 + ub) * 65 + bb] + xc2;
            float ov = gl[(24 + ub) * 65 + bb] + xc3;
            float ig = 1.f / (1.f + __expf(-iv));
            float fg = 1.f / (1.f + __expf(-fv));
            float gg = tanhf(gv);
            float og = 1.f / (1.f + __expf(-ov));
            float cn = fg * c_reg + ig * gg;
            float hn = og * tanhf(cn);
            c_reg = cn;

            short hi = f2bf(hn);
            Hs[bb][ub] = hi;
            if (t < 31) Ls[bb][ub] = f2bf(hn - bf2f(hi));
            __syncthreads();

            // ---- R11 publication ----
            // 1) Af stores (waves 0-3)
            if (t < 31 && tid < 256) {
                const short* src = rdt ? &Ls[rbb][rhf * 4] : &Hs[rbb][rhf * 4];
                short s0 = src[0], s1 = src[1], s2 = src[2], s3 = src[3];
                unsigned lo32 = (unsigned short)s0 | ((unsigned)(unsigned short)s1 << 16);
                unsigned hi32 = (unsigned short)s2 | ((unsigned)(unsigned short)s3 << 16);
                long long pv = ((long long)hi32 << 32) | (long long)lo32;
                short* dst = Af + (size_t)t * (AF2_FRAGS * 8) + roff;
                asm volatile("global_store_dwordx2 %0, %1, off sc0 sc1"
                             :: "v"(dst), "v"(pv) : "memory");
            }
            // 2) ISSUE-barrier: all waves' Af stores are in flight
            __builtin_amdgcn_s_barrier();
            asm volatile("" ::: "memory");
            // 3) rec flags fire immediately (no drain) — consumers validate
            if (t < 31 && tid == 0) {
#pragma unroll
                for (int rp = 0; rp < 8; ++rp)
                    __hip_atomic_store(&flags[rp * 64 + bid], t + 1,
                                       __ATOMIC_RELAXED, __HIP_MEMORY_SCOPE_AGENT);
            }
            // 4) hs2 publication for the GEMM workers (t-major, 16B per batch)
            if (tid < 64) {
                const short* hp = &Hs[tid][0];
                int4v pv;
                pv.x = (int)((unsigned short)hp[0] | ((unsigned)(unsigned short)hp[1] << 16));
                pv.y = (int)((unsigned short)hp[2] | ((unsigned)(unsigned short)hp[3] << 16));
                pv.z = (int)((unsigned short)hp[4] | ((unsigned)(unsigned short)hp[5] << 16));
                pv.w = (int)((unsigned short)hp[6] | ((unsigned)(unsigned short)hp[7] << 16));
                char* dst2 = (char*)(hs2 + ((size_t)t * 64 + tid) * 512 + j0);
                asm volatile("global_store_dwordx4 %0, %1, off sc0 sc1"
                             :: "v"(dst2), "v"(pv) : "memory");
            }
            // 5) drained release for the workers only
            if (tid < 256)
                asm volatile("s_waitcnt vmcnt(0)" ::: "memory");
            __builtin_amdgcn_s_barrier();
            asm volatile("" ::: "memory");
            if (tid == 0) {
#pragma unroll
                for (int rp = 0; rp < 8; ++rp)
                    __hip_atomic_store(&flags[512 + rp * 64 + bid], t + 1,
                                       __ATOMIC_RELAXED, __HIP_MEMORY_SCOPE_AGENT);
            }

            xc0 = xn0; xc1 = xn1; xc2 = xn2; xc3 = xn3;
        }
    } else {
        // ===================== logits-GEMM worker path =====================
        const int w   = bid - 64;         // 0..191
        const int wm2 = wave >> 2;        // 0..1  (64-row half)
        const int wn2 = wave & 3;         // 0..3  (32-col quarter)

        for (int task = w; task < 2000; task += 192) {
            const int bm = task / 125;    // 0..15 : steps {2bm, 2bm+1}
            const int bn = task % 125;
            const int target = 2 * bm + 2;

            if (tid < 64) {
                while (true) {
                    int f = __hip_atomic_load(&flags[512 + frep + tid], __ATOMIC_RELAXED,
                                              __HIP_MEMORY_SCOPE_AGENT);
                    if (!__any(f < target)) break;
                    __builtin_amdgcn_s_sleep(16);
                }
            }
            __syncthreads();

            float4v acc[4][2];
#pragma unroll
            for (int i = 0; i < 4; ++i)
#pragma unroll
                for (int j = 0; j < 2; ++j) acc[i][j] = (float4v)(0.0f);

            const long arow0 = (long)bm * 128;
            const long brow0 = (long)bn * 128;

            for (int kt = 0; kt < 512; kt += GBK) {
                __syncthreads();
#pragma unroll
                for (int it = 0; it < 2; ++it) {
                    int task2 = tid + it * 512;      // 0..1023
                    int row = task2 >> 3, seg = task2 & 7;
                    const short* gA = hs2 + (arow0 + row) * 512L + kt + seg * 8;
                    *(short8v*)&As[row * GLDT + seg * 8] = *(const short8v*)gA;
                    const short* gB = Wl + (brow0 + row) * 512L + kt + seg * 8;
                    *(short8v*)&Bs[row * GLDT + seg * 8] = *(const short8v*)gB;
                }
                __syncthreads();
#pragma unroll
                for (int kc = 0; kc < GBK; kc += 32) {
                    short8v af[4], bf[2];
#pragma unroll
                    for (int i = 0; i < 4; ++i) {
                        int arow = wm2 * 64 + i * 16 + r;
                        union { short4v h[2]; short8v v; } ua;
                        ua.h[0] = *(short4v*)&As[arow * GLDT + kc + q * 4];
                        ua.h[1] = *(short4v*)&As[arow * GLDT + kc + 16 + q * 4];
                        af[i] = ua.v;
                    }
#pragma unroll
                    for (int j = 0; j < 2; ++j) {
                        int brow = wn2 * 32 + j * 16 + r;
                        union { short4v h[2]; short8v v; } ub;
                        ub.h[0] = *(short4v*)&Bs[brow * GLDT + kc + q * 4];
                        ub.h[1] = *(short4v*)&Bs[brow * GLDT + kc + 16 + q * 4];
                        bf[j] = ub.v;
                    }
#pragma unroll
                    for (int i = 0; i < 4; ++i)
#pragma unroll
                        for (int j = 0; j < 2; ++j)
                            acc[i][j] = __builtin_amdgcn_mfma_f32_16x16x32_bf16(
                                af[i], bf[j], acc[i][j], 0, 0, 0);
                }
            }

            // epilogue: row m = bm*128 + lr, lr -> (t = m>>6, b = m&63)
#pragma unroll
            for (int j = 0; j < 2; ++j) {
                int col = bn * 128 + wn2 * 32 + j * 16 + r;
                float bv = b_lin[col];
#pragma unroll
                for (int i = 0; i < 4; ++i) {
                    int lr0 = wm2 * 64 + i * 16 + q * 4;
#pragma unroll
                    for (int reg = 0; reg < 4; ++reg) {
                        int m  = bm * 128 + lr0 + reg;
                        int tt = m >> 6, bb2 = m & 63;
                        out[((long)bb2 * 32 + tt) * 16000 + col] = acc[i][j][reg] + bv;
                    }
                }
            }
            __syncthreads();   // protect As/Bs before next task's staging
        }
    }
}

// ---------------------------------------------------------------------------
// launch
// ---------------------------------------------------------------------------
extern "C" void kernel_launch(void* const* d_in, const int* in_sizes, int n_in,
                              void* d_out, int out_size, void* d_ws, size_t ws_size,
                              hipStream_t stream) {
    const float* features = (const float*)d_in[0];
    const int*   captions = (const int*)d_in[1];
    const float* emb      = (const float*)d_in[2];
    const float* W_ih     = (const float*)d_in[3];
    const float* W_hh     = (const float*)d_in[4];
    const float* b_ih     = (const float*)d_in[5];
    const float* b_hh     = (const float*)d_in[6];
    const float* W_lin    = (const float*)d_in[7];
    const float* b_lin    = (const float*)d_in[8];
    float* out = (float*)d_out;

    char* ws = (char*)d_ws;
    float* x_proj = (float*)ws;  ws += 2048L * 2048 * 4;          // 16 MB
    short* A1     = (short*)ws;  ws += 2048L * 1536 * 2;          // 6 MB
    short* B1     = (short*)ws;  ws += 2048L * 1536 * 2;          // 6 MB (reused as W2)
    short* Wl     = (short*)ws;  ws += 16000L * 512 * 2;          // 16 MB
    short* hs2    = (short*)ws;  ws += 2048L * 512 * 2;           // 2 MB (t-major)
    float* biasc  = (float*)ws;  ws += 2048 * 4;
    int*   flags  = (int*)ws;    ws += 4096;                      // rec + wrk x8 replicas
    short* Af2    = (short*)ws;  ws += 31L * AF2_FRAGS * 8 * 2;   // 3.97 MB

    prep_x_kernel<<<2048, 256, 0, stream>>>(features, captions, emb, A1);
    prep_w_kernel<<<2048, 256, 0, stream>>>(W_ih, B1);
    prep_bias_kernel<<<8, 256, 0, stream>>>(b_ih, b_hh, biasc, flags);
    prep_wlin_kernel<<<16000, 256, 0, stream>>>(W_lin, Wl);
    poison_af_kernel<<<992, 256, 0, stream>>>(Af2);   // re-poison EVERY launch

    dim3 gA(16, 16);
    gemm_bf16_kernel<<<gA, 256, 0, stream>>>(A1, B1, biasc, x_proj,
                                             2048, 2048, 1536);

    // B1 is dead after the x_proj GEMM; reuse its 6 MB for W_hh' fragments.
    prep_whh_kernel<<<2048, 256, 0, stream>>>(W_hh, B1);

    fused_lstm_logits_kernel<<<256, 512, 0, stream>>>(
        x_proj, B1, Af2, hs2, flags, Wl, b_lin, out);
}

// Round 12
// 248.589 us; speedup vs baseline: 1.9647x; 1.9647x over previous
//
#include <hip/hip_runtime.h>
#include <hip/hip_bf16.h>

// ---------------------------------------------------------------------------
// DecoderRNN: emb gather (t-major A1) -> ONE fused kernel:
//   blocks 64-255 = persistent workers: first 256 x_proj GEMM tasks
//     (K=1536, t-major M, per-M-tile drained counters), then 2000 logits
//     GEMM tasks (K=512) gated on LSTM step flags;
//   blocks 0-63  = persistent dataflow LSTM (R9-proven drained publication),
//     x_proj reads gated per-M-tile with prefetched counters, Wf built
//     in-kernel from W_hh (no prep_whh / W2).
// B=64 T=32 E=512 H=512 V=16000
// ---------------------------------------------------------------------------

typedef __attribute__((ext_vector_type(8))) short short8v;
typedef __attribute__((ext_vector_type(4))) short short4v;
typedef __attribute__((ext_vector_type(4))) float float4v;
typedef __attribute__((ext_vector_type(4))) int   int4v;

static __device__ __forceinline__ short f2bf(float v) {
    __hip_bfloat16 b = __float2bfloat16(v);
    return *reinterpret_cast<short*>(&b);
}
static __device__ __forceinline__ float bf2f(short s) {
    __hip_bfloat16 b = *reinterpret_cast<__hip_bfloat16*>(&s);
    return __bfloat162float(b);
}

// ---------------------------------------------------------------------------
// Prep kernels
// ---------------------------------------------------------------------------

// Build A' for x_proj GEMM, T-MAJOR rows: m = t*64 + b, content
// [hi(x), lo(x), hi(x)], x = features[b] (t==0) else emb[captions[b,t]].
__global__ __launch_bounds__(256) void prep_x_kernel(
    const float* __restrict__ features, const int* __restrict__ captions,
    const float* __restrict__ emb, short* __restrict__ A1)
{
    int m = blockIdx.x;            // 0..2047 = t*64 + b
    int t = m >> 6, b = m & 63;
    const float* src = (t == 0) ? (features + (long)b * 512)
                                : (emb + (long)captions[b * 32 + t] * 512);
    long base = (long)m * 1536;
    for (int k = threadIdx.x; k < 512; k += 256) {
        float v = src[k];
        short hi = f2bf(v);
        short lo = f2bf(v - bf2f(hi));
        A1[base + k]        = hi;
        A1[base + 512 + k]  = lo;
        A1[base + 1024 + k] = hi;
    }
}

// Build B' for W_ih: rows n (gate dim), content [hi(w), hi(w), lo(w)].
__global__ __launch_bounds__(256) void prep_w_kernel(
    const float* __restrict__ W_ih, short* __restrict__ B1)
{
    int n = blockIdx.x;            // 0..2047
    long base = (long)n * 1536;
    const float* src = W_ih + (long)n * 512;
    for (int k = threadIdx.x; k < 512; k += 256) {
        float v = src[k];
        short hi = f2bf(v);
        short lo = f2bf(v - bf2f(hi));
        B1[base + k]        = hi;
        B1[base + 512 + k]  = hi;
        B1[base + 1024 + k] = lo;
    }
}

__global__ __launch_bounds__(256) void prep_bias_kernel(
    const float* __restrict__ b_ih, const float* __restrict__ b_hh,
    float* __restrict__ biasc, int* __restrict__ flags)
{
    int g = blockIdx.x * 256 + threadIdx.x;
    if (g < 2048) biasc[g] = b_ih[g] + b_hh[g];
    if (g < 640)  flags[g] = 0;   // [0..511] step flags x8, [512..639] xpc x8
}

// W_lin fp32 -> bf16.  Wl: [16000][512] bf16
__global__ __launch_bounds__(256) void prep_wlin_kernel(
    const float* __restrict__ W_lin, short* __restrict__ Wl)
{
    int v = blockIdx.x;            // 0..15999
    long base = (long)v * 512;
    for (int k = threadIdx.x; k < 512; k += 256) {
        Wl[base + k] = f2bf(W_lin[base + k]);
    }
}

// ---------------------------------------------------------------------------
// Fragment layout for the LSTM recurrence ([hi | lo] compressed, 32 k-tiles).
// Af buffer (per step): [4 mt][32 kt][64 lane][8] bf16 = 128 KB
// Wf (per block LDS):   [2 nt][32 kt][64 lane][8] bf16 = 64 KB.
// ---------------------------------------------------------------------------
#define AF2_FRAGS 8192           // 4 * 32 * 64
#define W3_FRAGS_PER_BLK 4096    // 2 * 32 * 64

static __device__ __forceinline__ int frag2_idx(int tile, int k, int row15, int isLo)
{
    return ((tile * 32 + (k >> 5) + isLo * 16) * 64
            + ((k >> 2) & 3) * 16 + row15) * 8
           + (k & 3) + ((k >> 4) & 1) * 4;
}

#define GBK 64
#define GPAD 8
#define GLDT (GBK + GPAD)   // 72 shorts per row

// ---------------------------------------------------------------------------
// Fused persistent kernel, 256 blocks x 512 threads (1 block/CU):
//  blocks 0-63:  dataflow LSTM.  Wf built in-kernel from W_hh; x_proj reads
//    gated on per-M-tile counters (prefetched; free once satisfied);
//    R9-proven publication: Af+hs2 sc1 stores -> vmcnt(0) -> syncthreads ->
//    step flags x8 replicas.
//  blocks 64-255: workers.  Tasks 0..255 = x_proj GEMM (K=1536, t-major,
//    sc1 fp32 epilogue, drained counter release).  Tasks 256..2255 = logits
//    GEMM (K=512) gated on step flags (replica bid&7, s_sleep poll).
// ---------------------------------------------------------------------------
__global__ __launch_bounds__(512, 1) void fused_lstm_logits_kernel(
    float* __restrict__ x_proj, const float* __restrict__ W_hh,
    const short* __restrict__ A1, const short* __restrict__ B1,
    const float* __restrict__ biasc,
    short* __restrict__ Af, short* __restrict__ hs2,
    int* __restrict__ flags, const short* __restrict__ Wl,
    const float* __restrict__ b_lin, float* __restrict__ out)
{
    // LSTM-side LDS
    __shared__ __align__(16) short Wf[W3_FRAGS_PER_BLK * 8];  // 64 KB
    __shared__ float gl[32 * 65];                             // 8.3 KB
    __shared__ short Hs[64][12];                              // 1.5 KB
    __shared__ short Ls[64][12];                              // 1.5 KB
    // worker-side LDS
    __shared__ short As[128 * GLDT];                          // 18 KB
    __shared__ short Bs[128 * GLDT];                          // 18 KB

    const int tid  = threadIdx.x;
    const int bid  = blockIdx.x;
    const int lane = tid & 63;
    const int wave = tid >> 6;        // 0..7
    const int r    = lane & 15, q = lane >> 4;
    const int frep   = (bid & 7) * 64;   // step-flag replica base
    const int frep16 = (bid & 7) * 16;   // xpc replica base
    int* __restrict__ xpc = flags + 512; // [8 reps][16 m-tiles]

    if (bid < 64) {
        // ===================== LSTM path =====================
        const int mt   = wave & 3;        // batch tile (16 rows each)
        const int nt   = wave >> 2;       // gate-col tile (16 cols each)
        const int j0   = bid * 8;
        const int aq   = bid & 3;         // k5 block within 32-wide k-tile
        const int kt0  = bid >> 2;        // k-tile our jj values live in

        // build Wf in-kernel from W_hh (32 gate-rows, hi/lo split).
        // iteration i: row nl=i (n = (nl>>3)*512 + j0 + (nl&7)), k = tid.
        for (int i = 0; i < 32; ++i) {
            int nl = i;
            int s2 = nl >> 3, u2 = nl & 7;
            int nt2 = nl >> 4, rr2 = nl & 15;
            float v = W_hh[((long)s2 * 512 + j0 + u2) * 512 + tid];
            short hi2 = f2bf(v);
            short lo2 = f2bf(v - bf2f(hi2));
            Wf[frag2_idx(nt2, tid, rr2, 0)] = hi2;
            Wf[frag2_idx(nt2, tid, rr2, 1)] = lo2;
        }
        __syncthreads();

        const int bb  = lane;
        const int ub  = wave;             // 0..7
        const int jj  = j0 + ub;
        float c_reg = 0.0f;

        // repack-task decode (threads 0..255): one 8B Af store each
        const int rdt  = (tid >> 7) & 1;          // 0=hi, 1=lo
        const int rmt  = (tid >> 5) & 3;
        const int rrb  = (tid >> 1) & 15;
        const int rhf  = tid & 1;
        const int rbb  = rmt * 16 + rrb;
        const int rq5  = (2 * aq + rhf) & 3;
        const size_t rfrag =
            (size_t)((rmt * 32 + kt0 + rdt * 16) * 64 + rq5 * 16 + rrb);
        const size_t roff = rfrag * 8 + (size_t)(aq >> 1) * 4;

        const short8v* Bw = (const short8v*)Wf + nt * 32 * 64 + lane;

        // gate on x_proj m-tile 0 (covers steps 0,1), then load step-0 xc
        if (tid == 0) {
            while (__hip_atomic_load(&xpc[frep16 + 0], __ATOMIC_RELAXED,
                                     __HIP_MEMORY_SCOPE_AGENT) < 16)
                __builtin_amdgcn_s_sleep(4);
        }
        __syncthreads();

        float xc0, xc1, xc2, xc3;
        {
            const float* xp = x_proj + ((size_t)0 * 64 + bb) * 2048 + jj;
            xc0 = xp[0]; xc1 = xp[512]; xc2 = xp[1024]; xc3 = xp[1536];
        }
        int xpn = 16;   // prefetched counter for tile (t+1)>>1 (tile 0 done)

        for (int t = 0; t < 32; ++t) {
            float xn0 = 0.f, xn1 = 0.f, xn2 = 0.f, xn3 = 0.f;
            if (t < 31) {
                int nbm = (t + 1) >> 1;
                if (xpn < 16) {     // stale-positive is safe (monotonic)
                    while (__hip_atomic_load(&xpc[frep16 + nbm], __ATOMIC_RELAXED,
                                             __HIP_MEMORY_SCOPE_AGENT) < 16)
                        __builtin_amdgcn_s_sleep(2);
                }
                const float* xp = x_proj + ((size_t)(t + 1) * 64 + bb) * 2048 + jj;
                xn0 = xp[0]; xn1 = xp[512]; xn2 = xp[1024]; xn3 = xp[1536];
                int fbm = (t + 2) >> 1; if (fbm > 15) fbm = 15;
                xpn = __hip_atomic_load(&xpc[frep16 + fbm], __ATOMIC_RELAXED,
                                        __HIP_MEMORY_SCOPE_AGENT);
            }

            float4v acc = (float4v)(0.0f);
            if (t > 0) {
                const short8v* Ab = (const short8v*)Af
                    + (size_t)(t - 1) * AF2_FRAGS + mt * 32 * 64 + lane;
                short8v Ahi[16], Alo[16];

                unsigned long long ready;
                {
                    int myf = __hip_atomic_load(&flags[frep + lane], __ATOMIC_RELAXED,
                                                __HIP_MEMORY_SCOPE_AGENT);
                    ready = __ballot(myf >= t);
                }
#pragma unroll
                for (int g = 0; g < 4; ++g) {
                    const unsigned long long need = 0xFFFFull << (g * 16);
                    while ((ready & need) != need) {
                        int myf = __hip_atomic_load(&flags[frep + lane], __ATOMIC_RELAXED,
                                                    __HIP_MEMORY_SCOPE_AGENT);
                        ready = __ballot(myf >= t);
                    }
                    asm volatile("" ::: "memory");
#pragma unroll
                    for (int k = 0; k < 4; ++k) {
                        Ahi[g * 4 + k] = Ab[(g * 4 + k) * 64];
                        Alo[g * 4 + k] = Ab[(16 + g * 4 + k) * 64];
                    }
                }

                float4v a0 = (float4v)(0.0f), a1 = (float4v)(0.0f), a2 = (float4v)(0.0f);
#pragma unroll
                for (int kt = 0; kt < 16; ++kt) {
                    short8v Bhi = Bw[kt * 64];
                    short8v Blo = Bw[(16 + kt) * 64];
                    a0 = __builtin_amdgcn_mfma_f32_16x16x32_bf16(Ahi[kt], Bhi, a0, 0, 0, 0);
                    a1 = __builtin_amdgcn_mfma_f32_16x16x32_bf16(Alo[kt], Bhi, a1, 0, 0, 0);
                    a2 = __builtin_amdgcn_mfma_f32_16x16x32_bf16(Ahi[kt], Blo, a2, 0, 0, 0);
                }
                acc = a0 + a1 + a2;
            }

            __syncthreads();
#pragma unroll
            for (int reg = 0; reg < 4; ++reg)
                gl[(nt * 16 + r) * 65 + mt * 16 + q * 4 + reg] = acc[reg];
            __syncthreads();

            float iv = gl[(0  + ub) * 65 + bb] + xc0;
            float fv = gl[(8  + ub) * 65 + bb] + xc1;
            float gv = gl[(16 + ub) * 65 + bb] + xc2;
            float ov = gl[(24 + ub) * 65 + bb] + xc3;
            float ig = 1.f / (1.f + __expf(-iv));
            float fg = 1.f / (1.f + __expf(-fv));
            float gg = tanhf(gv);
            float og = 1.f / (1.f + __expf(-ov));
            float cn = fg * c_reg + ig * gg;
            float hn = og * tanhf(cn);
            c_reg = cn;

            short hi = f2bf(hn);
            Hs[bb][ub] = hi;
            if (t < 31) Ls[bb][ub] = f2bf(hn - bf2f(hi));
            __syncthreads();

            // ---- R9-proven drained publication ----
            if (tid < 256) {
                if (t < 31) {
                    const short* src = rdt ? &Ls[rbb][rhf * 4] : &Hs[rbb][rhf * 4];
                    short s0 = src[0], s1 = src[1], s2 = src[2], s3 = src[3];
                    unsigned lo32 = (unsigned short)s0 | ((unsigned)(unsigned short)s1 << 16);
                    unsigned hi32 = (unsigned short)s2 | ((unsigned)(unsigned short)s3 << 16);
                    long long pv = ((long long)hi32 << 32) | (long long)lo32;
                    short* dst = Af + (size_t)t * (AF2_FRAGS * 8) + roff;
                    asm volatile("global_store_dwordx2 %0, %1, off sc0 sc1"
                                 :: "v"(dst), "v"(pv) : "memory");
                }
                if (tid < 64) {
                    const short* hp = &Hs[tid][0];
                    int4v pv;
                    pv.x = (int)((unsigned short)hp[0] | ((unsigned)(unsigned short)hp[1] << 16));
                    pv.y = (int)((unsigned short)hp[2] | ((unsigned)(unsigned short)hp[3] << 16));
                    pv.z = (int)((unsigned short)hp[4] | ((unsigned)(unsigned short)hp[5] << 16));
                    pv.w = (int)((unsigned short)hp[6] | ((unsigned)(unsigned short)hp[7] << 16));
                    char* dst2 = (char*)(hs2 + ((size_t)t * 64 + tid) * 512 + j0);
                    asm volatile("global_store_dwordx4 %0, %1, off sc0 sc1"
                                 :: "v"(dst2), "v"(pv) : "memory");
                }
                asm volatile("s_waitcnt vmcnt(0)" ::: "memory");
            }
            __syncthreads();   // all publication stores drained
            if (tid == 0) {
#pragma unroll
                for (int rp = 0; rp < 8; ++rp)
                    __hip_atomic_store(&flags[rp * 64 + bid], t + 1,
                                       __ATOMIC_RELAXED, __HIP_MEMORY_SCOPE_AGENT);
            }

            xc0 = xn0; xc1 = xn1; xc2 = xn2; xc3 = xn3;
        }
    } else {
        // ===================== worker path =====================
        const int w   = bid - 64;         // 0..191
        const int wm2 = wave >> 2;        // 0..1  (64-row half)
        const int wn2 = wave & 3;         // 0..3  (32-col quarter)

        for (int task = w; task < 2256; task += 192) {
            if (task < 256) {
                // ---- x_proj GEMM task: 128x128 tile, K=1536, t-major M ----
                const int bm = task >> 4;     // m-tile (steps 2bm,2bm+1)
                const int bn = task & 15;     // gate-dim n-tile

                float4v acc[4][2];
#pragma unroll
                for (int i = 0; i < 4; ++i)
#pragma unroll
                    for (int j = 0; j < 2; ++j) acc[i][j] = (float4v)(0.0f);

                const long arow0 = (long)bm * 128;
                const long brow0 = (long)bn * 128;

                for (int kt = 0; kt < 1536; kt += GBK) {
                    __syncthreads();
#pragma unroll
                    for (int it = 0; it < 2; ++it) {
                        int t2 = tid + it * 512;      // 0..1023
                        int row = t2 >> 3, seg = t2 & 7;
                        const short* gA = A1 + (arow0 + row) * 1536L + kt + seg * 8;
                        *(short8v*)&As[row * GLDT + seg * 8] = *(const short8v*)gA;
                        const short* gB = B1 + (brow0 + row) * 1536L + kt + seg * 8;
                        *(short8v*)&Bs[row * GLDT + seg * 8] = *(const short8v*)gB;
                    }
                    __syncthreads();
#pragma unroll
                    for (int kc = 0; kc < GBK; kc += 32) {
                        short8v af[4], bf[2];
#pragma unroll
                        for (int i = 0; i < 4; ++i) {
                            int arow = wm2 * 64 + i * 16 + r;
                            union { short4v h[2]; short8v v; } ua;
                            ua.h[0] = *(short4v*)&As[arow * GLDT + kc + q * 4];
                            ua.h[1] = *(short4v*)&As[arow * GLDT + kc + 16 + q * 4];
                            af[i] = ua.v;
                        }
#pragma unroll
                        for (int j = 0; j < 2; ++j) {
                            int brow = wn2 * 32 + j * 16 + r;
                            union { short4v h[2]; short8v v; } ub;
                            ub.h[0] = *(short4v*)&Bs[brow * GLDT + kc + q * 4];
                            ub.h[1] = *(short4v*)&Bs[brow * GLDT + kc + 16 + q * 4];
                            bf[j] = ub.v;
                        }
#pragma unroll
                        for (int i = 0; i < 4; ++i)
#pragma unroll
                            for (int j = 0; j < 2; ++j)
                                acc[i][j] = __builtin_amdgcn_mfma_f32_16x16x32_bf16(
                                    af[i], bf[j], acc[i][j], 0, 0, 0);
                    }
                }

                // epilogue: fp32 + bias, sc1 write-through (cross-XCD readers)
#pragma unroll
                for (int j = 0; j < 2; ++j) {
                    int col = bn * 128 + wn2 * 32 + j * 16 + r;
                    float bv = biasc[col];
#pragma unroll
                    for (int i = 0; i < 4; ++i) {
                        int row0 = bm * 128 + wm2 * 64 + i * 16 + q * 4;
#pragma unroll
                        for (int reg = 0; reg < 4; ++reg) {
                            float vv = acc[i][j][reg] + bv;
                            float* dst = x_proj + (size_t)(row0 + reg) * 2048 + col;
                            asm volatile("global_store_dword %0, %1, off sc0 sc1"
                                         :: "v"(dst), "v"(vv) : "memory");
                        }
                    }
                }
                asm volatile("s_waitcnt vmcnt(0)" ::: "memory");
                __syncthreads();   // all threads' stores drained
                if (tid == 0) {
#pragma unroll
                    for (int rp = 0; rp < 8; ++rp)
                        __hip_atomic_fetch_add(&xpc[rp * 16 + bm], 1,
                                               __ATOMIC_RELAXED,
                                               __HIP_MEMORY_SCOPE_AGENT);
                }
            } else {
                // ---- logits GEMM task: 128x128 tile, K=512 ----
                const int lt = task - 256;
                const int bm = lt / 125;      // steps {2bm, 2bm+1}
                const int bn = lt % 125;
                const int target = 2 * bm + 2;

                if (tid < 64) {
                    while (true) {
                        int f = __hip_atomic_load(&flags[frep + tid], __ATOMIC_RELAXED,
                                                  __HIP_MEMORY_SCOPE_AGENT);
                        if (!__any(f < target)) break;
                        __builtin_amdgcn_s_sleep(16);
                    }
                }
                __syncthreads();

                float4v acc[4][2];
#pragma unroll
                for (int i = 0; i < 4; ++i)
#pragma unroll
                    for (int j = 0; j < 2; ++j) acc[i][j] = (float4v)(0.0f);

                const long arow0 = (long)bm * 128;
                const long brow0 = (long)bn * 128;

                for (int kt = 0; kt < 512; kt += GBK) {
                    __syncthreads();
#pragma unroll
                    for (int it = 0; it < 2; ++it) {
                        int t2 = tid + it * 512;      // 0..1023
                        int row = t2 >> 3, seg = t2 & 7;
                        const short* gA = hs2 + (arow0 + row) * 512L + kt + seg * 8;
                        *(short8v*)&As[row * GLDT + seg * 8] = *(const short8v*)gA;
                        const short* gB = Wl + (brow0 + row) * 512L + kt + seg * 8;
                        *(short8v*)&Bs[row * GLDT + seg * 8] = *(const short8v*)gB;
                    }
                    __syncthreads();
#pragma unroll
                    for (int kc = 0; kc < GBK; kc += 32) {
                        short8v af[4], bf[2];
#pragma unroll
                        for (int i = 0; i < 4; ++i) {
                            int arow = wm2 * 64 + i * 16 + r;
                            union { short4v h[2]; short8v v; } ua;
                            ua.h[0] = *(short4v*)&As[arow * GLDT + kc + q * 4];
                            ua.h[1] = *(short4v*)&As[arow * GLDT + kc + 16 + q * 4];
                            af[i] = ua.v;
                        }
#pragma unroll
                        for (int j = 0; j < 2; ++j) {
                            int brow = wn2 * 32 + j * 16 + r;
                            union { short4v h[2]; short8v v; } ub;
                            ub.h[0] = *(short4v*)&Bs[brow * GLDT + kc + q * 4];
                            ub.h[1] = *(short4v*)&Bs[brow * GLDT + kc + 16 + q * 4];
                            bf[j] = ub.v;
                        }
#pragma unroll
                        for (int i = 0; i < 4; ++i)
#pragma unroll
                            for (int j = 0; j < 2; ++j)
                                acc[i][j] = __builtin_amdgcn_mfma_f32_16x16x32_bf16(
                                    af[i], bf[j], acc[i][j], 0, 0, 0);
                    }
                }

                // epilogue: row m = bm*128 + lr -> (t = m>>6, b = m&63)
#pragma unroll
                for (int j = 0; j < 2; ++j) {
                    int col = bn * 128 + wn2 * 32 + j * 16 + r;
                    float bv = b_lin[col];
#pragma unroll
                    for (int i = 0; i < 4; ++i) {
                        int lr0 = wm2 * 64 + i * 16 + q * 4;
#pragma unroll
                        for (int reg = 0; reg < 4; ++reg) {
                            int m  = bm * 128 + lr0 + reg;
                            int tt = m >> 6, bb2 = m & 63;
                            out[((long)bb2 * 32 + tt) * 16000 + col] = acc[i][j][reg] + bv;
                        }
                    }
                }
            }
            __syncthreads();   // protect As/Bs before next task's staging
        }
    }
}

// ---------------------------------------------------------------------------
// launch
// ---------------------------------------------------------------------------
extern "C" void kernel_launch(void* const* d_in, const int* in_sizes, int n_in,
                              void* d_out, int out_size, void* d_ws, size_t ws_size,
                              hipStream_t stream) {
    const float* features = (const float*)d_in[0];
    const int*   captions = (const int*)d_in[1];
    const float* emb      = (const float*)d_in[2];
    const float* W_ih     = (const float*)d_in[3];
    const float* W_hh     = (const float*)d_in[4];
    const float* b_ih     = (const float*)d_in[5];
    const float* b_hh     = (const float*)d_in[6];
    const float* W_lin    = (const float*)d_in[7];
    const float* b_lin    = (const float*)d_in[8];
    float* out = (float*)d_out;

    char* ws = (char*)d_ws;
    float* x_proj = (float*)ws;  ws += 2048L * 2048 * 4;          // 16 MB (t-major)
    short* A1     = (short*)ws;  ws += 2048L * 1536 * 2;          // 6 MB (t-major)
    short* B1     = (short*)ws;  ws += 2048L * 1536 * 2;          // 6 MB
    short* Wl     = (short*)ws;  ws += 16000L * 512 * 2;          // 16 MB
    short* hs2    = (short*)ws;  ws += 2048L * 512 * 2;           // 2 MB (t-major)
    float* biasc  = (float*)ws;  ws += 2048 * 4;
    int*   flags  = (int*)ws;    ws += 4096;                      // step flags + xpc
    short* Af2    = (short*)ws;  ws += 31L * AF2_FRAGS * 8 * 2;   // 3.97 MB

    prep_x_kernel<<<2048, 256, 0, stream>>>(features, captions, emb, A1);
    prep_w_kernel<<<2048, 256, 0, stream>>>(W_ih, B1);
    prep_bias_kernel<<<8, 256, 0, stream>>>(b_ih, b_hh, biasc, flags);
    prep_wlin_kernel<<<16000, 256, 0, stream>>>(W_lin, Wl);

    fused_lstm_logits_kernel<<<256, 512, 0, stream>>>(
        x_proj, W_hh, A1, B1, biasc, Af2, hs2, flags, Wl, b_lin, out);
}